// Round 5
// baseline (175.573 us; speedup 1.0000x reference)
//
#include <hip/hip_runtime.h>

#define BATCH 1024
#define NEG 64
#define KNB 128
#define FD 128
#define NV 200
#define NSLAB 8
#define SUMW (5 * NV + 1)   // 5 column-sum arrays + loss accumulator per slab
#define NBLK (BATCH + NEG)

__device__ __forceinline__ float log_sig(float x) {
    // log(sigmoid(x) + 0.001); saturates correctly at both ends
    float s = 1.0f / (1.0f + expf(-x));
    return logf(s + 0.001f);
}

// ---- fused main kernel (round-1 body, verified 41.6us total) ----
// 512 threads = 8 waves per block; __launch_bounds__(512,8) caps VGPR<=64 so
// 4 blocks/CU = 32 waves/CU.
// Gather is the measured floor (~4.2 TB/s random-row via L3; MLP x2 = null,
// bytes/2 = net loss): keep this region byte-identical. Only change this
// round: the finale is folded in via last-block-done (saves final_kernel's
// launch + gap).
// b < 1024: waves 0-3 gather the inf row (32 nbrs each), waves 4-7 the lf row,
//           then p1/p3/p5/p7 dots + slabbed column-sum atomics.
// b >= 1024: one neg row, 8 waves x 16 nbrs.
__global__ __launch_bounds__(512, 8) void fused_kernel(
    const int* __restrict__ ti, const int* __restrict__ tl, const int* __restrict__ ns,
    const int* __restrict__ rpr_arg, const float* __restrict__ rpr_mat,
    const float* __restrict__ feat, const float* __restrict__ W,
    const float* __restrict__ emb, const float* __restrict__ nce,
    float* __restrict__ sums, float* __restrict__ out)
{
    int b = blockIdx.x, t = threadIdx.x, lane = t & 63, w = t >> 6;
    bool pair = (b < BATCH);
    // slab layout: [0,NV) sumInf | [NV,2NV) sumNf | [2NV,3NV) sumEmb
    //              [3NV,4NV) sumTw | [4NV,5NV) sumFw | [5NV] lossAcc
    float* slab = sums + (size_t)(b & (NSLAB - 1)) * SUMW;

    __shared__ int   nbr_sh[256];
    __shared__ float w_sh[256];
    __shared__ float part[8][FD];
    __shared__ float agg_i[FD], agg_l[FD];
    __shared__ float red[5][8];
    __shared__ unsigned isLast;

    if (pair) {
        if (t < 256) {
            int idx = (t < 128) ? ti[b] : tl[b];      // wave-uniform scalar load
            nbr_sh[t] = rpr_arg[(size_t)idx * KNB + (t & 127)];
            w_sh[t]   = rpr_mat[(size_t)idx * KNB + (t & 127)];
        }
    } else if (t < 128) {
        int idx = ns[b - BATCH];
        nbr_sh[t] = rpr_arg[(size_t)idx * KNB + t];
        w_sh[t]   = rpr_mat[(size_t)idx * KNB + t];
    }
    __syncthreads();

    float accX = 0.f, accY = 0.f;
    {
        // pair: waves 0-3 cover nbr [0,128) (inf), waves 4-7 cover [128,256) (lf)
        // neg:  8 waves share the single row's 128 neighbors
        int nb   = pair ? 4 : 2;                  // batches of 8
        int base = pair ? (w * 32) : (w * 16);
        for (int bb = 0; bb < nb; ++bb) {
            int k0 = base + bb * 8;
            float2 d[8]; float ww[8];
            #pragma unroll
            for (int j = 0; j < 8; ++j) {
                ww[j] = w_sh[k0 + j];
                d[j]  = *(const float2*)&feat[(size_t)(unsigned)nbr_sh[k0 + j] * FD + 2 * lane];
            }
            #pragma unroll
            for (int j = 0; j < 8; ++j) {
                accX += ww[j] * d[j].x;
                accY += ww[j] * d[j].y;
            }
        }
    }
    ((float2*)part[w])[lane] = make_float2(accX, accY);   // cols 2*lane, 2*lane+1
    __syncthreads();

    if (pair) {
        if (t < FD)
            agg_i[t] = part[0][t] + part[1][t] + part[2][t] + part[3][t];
        else if (t < 2 * FD) {
            int u = t - FD;
            agg_l[u] = part[4][u] + part[5][u] + part[6][u] + part[7][u];
        }
    } else if (t < FD) {
        agg_i[t] = part[0][t] + part[1][t] + part[2][t] + part[3][t]
                 + part[4][t] + part[5][t] + part[6][t] + part[7][t];
    }
    __syncthreads();

    // dense [128]x[128,200] + relu; one W pass serves both rows
    float pi = 0.f, pl = 0.f;
    if (t < NV) {
        if (pair) {
            #pragma unroll 8
            for (int f = 0; f < FD; ++f) {
                float wv = W[f * NV + t];
                pi += agg_i[f] * wv;
                pl += agg_l[f] * wv;
            }
            pl = fmaxf(pl, 0.f);
        } else {
            #pragma unroll 8
            for (int f = 0; f < FD; ++f)
                pi += agg_i[f] * W[f * NV + t];
        }
        pi = fmaxf(pi, 0.f);
    }

    if (pair) {
        float e = 0.f, tw = 0.f;
        if (t < NV) {
            e  = emb[(size_t)ti[b] * NV + t];
            tw = nce[(size_t)tl[b] * NV + t];
            atomicAdd(&slab[t], pi);            // sumInf
            atomicAdd(&slab[2 * NV + t], e);    // sumEmb
            atomicAdd(&slab[3 * NV + t], tw);   // sumTw
        }
        float v0 = pi * pl;   // p1
        float v1 = e * tw;    // p3
        float v2 = e * pl;    // p5
        float v3 = tw * pi;   // p7
        #pragma unroll
        for (int o = 32; o > 0; o >>= 1) {
            v0 += __shfl_down(v0, o, 64);
            v1 += __shfl_down(v1, o, 64);
            v2 += __shfl_down(v2, o, 64);
            v3 += __shfl_down(v3, o, 64);
        }
        if (lane == 0) {
            red[0][w] = v0; red[1][w] = v1; red[2][w] = v2; red[3][w] = v3;
        }
        __syncthreads();
        if (t == 0) {
            float d1 = 0.f, d3 = 0.f, d5 = 0.f, d7 = 0.f;
            #pragma unroll
            for (int i = 0; i < 8; ++i) {
                d1 += red[0][i]; d3 += red[1][i]; d5 += red[2][i]; d7 += red[3][i];
            }
            float s = 1.5f * log_sig(d1) + 0.75f * log_sig(d3)
                    + 1.5f * log_sig(d5) + 1.5f * log_sig(d7);
            atomicAdd(&slab[5 * NV], s);
        }
    } else {
        if (t < NV) {
            atomicAdd(&slab[NV + t], pi);                                       // sumNf
            atomicAdd(&slab[4 * NV + t], nce[(size_t)ns[b - BATCH] * NV + t]);  // sumFw
        }
    }

    // ---- last-block-done finale (replaces final_kernel launch) ----
    __threadfence();
    __syncthreads();
    if (t == 0)
        isLast = (atomicAdd((unsigned*)&sums[NSLAB * SUMW], 1u) == NBLK - 1);
    __syncthreads();
    if (isLast) {
        __threadfence();
        float a = 0.f, b2 = 0.f, c = 0.f, d = 0.f, lp = 0.f;
        if (t < NV) {
            float si = 0.f, sn = 0.f, se = 0.f, st = 0.f, sf = 0.f;
            #pragma unroll
            for (int s = 0; s < NSLAB; ++s) {
                const float* p = sums + s * SUMW;
                si += p[t];          sn += p[NV + t];     se += p[2 * NV + t];
                st += p[3 * NV + t]; sf += p[4 * NV + t];
            }
            a  = si * sn;   // sum(inf @ nf.T)
            b2 = se * sf;   // sum(embed @ false_w.T)
            c  = se * sn;   // sum(embed @ nf.T)
            d  = st * sn;   // sum(true_w @ nf.T)
        }
        if (t < NSLAB) lp = sums[t * SUMW + 5 * NV];
        #pragma unroll
        for (int o = 32; o > 0; o >>= 1) {
            a  += __shfl_down(a, o, 64);
            b2 += __shfl_down(b2, o, 64);
            c  += __shfl_down(c, o, 64);
            d  += __shfl_down(d, o, 64);
            lp += __shfl_down(lp, o, 64);
        }
        if (lane == 0) {
            red[0][w] = a; red[1][w] = b2; red[2][w] = c; red[3][w] = d; red[4][w] = lp;
        }
        __syncthreads();
        if (t == 0) {
            float d2 = 0.f, d4 = 0.f, d6 = 0.f, d8 = 0.f, lacc = 0.f;
            #pragma unroll
            for (int i = 0; i < 8; ++i) {
                d2 += red[0][i]; d4 += red[1][i]; d6 += red[2][i]; d8 += red[3][i];
                lacc += red[4][i];
            }
            float total = lacc + (float)BATCH *
                (1.5f * log_sig(-d2) + 0.75f * log_sig(-d4)
               + 1.5f * log_sig(-d6) + 1.5f * log_sig(-d8));
            out[0] = -total / (float)BATCH;
        }
    }
}

extern "C" void kernel_launch(void* const* d_in, const int* in_sizes, int n_in,
                              void* d_out, int out_size, void* d_ws, size_t ws_size,
                              hipStream_t stream) {
    const int*   ti      = (const int*)d_in[0];
    const int*   tl      = (const int*)d_in[1];
    const int*   ns      = (const int*)d_in[2];
    const int*   rpr_arg = (const int*)d_in[3];
    const float* rpr_mat = (const float*)d_in[4];
    const float* feat    = (const float*)d_in[5];
    const float* emb     = (const float*)d_in[6];
    const float* nce     = (const float*)d_in[7];
    const float* W       = (const float*)d_in[8];

    float* sums = (float*)d_ws;   // NSLAB*SUMW floats + 1 counter word = ~32 KB

    hipMemsetAsync(d_ws, 0, ((size_t)NSLAB * SUMW + 1) * sizeof(float), stream);
    fused_kernel<<<NBLK, 512, 0, stream>>>(
        ti, tl, ns, rpr_arg, rpr_mat, feat, W, emb, nce, sums, (float*)d_out);
}

// Round 6
// 41.538 us; speedup vs baseline: 4.2268x; 4.2268x over previous
//
#include <hip/hip_runtime.h>

#define BATCH 1024
#define NEG 64
#define KNB 128
#define FD 128
#define NV 200
#define NSLAB 8
#define SUMW (5 * NV + 1)   // 5 column-sum arrays + loss accumulator per slab

__device__ __forceinline__ float log_sig(float x) {
    // log(sigmoid(x) + 0.001); saturates correctly at both ends
    float s = 1.0f / (1.0f + expf(-x));
    return logf(s + 0.001f);
}

// ---- fused main kernel ----
// 512 threads = 8 waves per block; __launch_bounds__(512,8) caps VGPR<=64 so
// 4 blocks/CU = 32 waves/CU (vs 17 before).
// b < 1024: waves 0-3 gather the inf row (32 nbrs each), waves 4-7 the lf row,
//           then p1/p3/p5/p7 dots + slabbed column-sum atomics.
// b >= 1024: one neg row, 8 waves x 16 nbrs.
// Gather reads f32 features directly (no bf16 table / convert pass): each lane
// owns columns (2*lane, 2*lane+1) via one float2 load per neighbor row; 8 loads
// kept in flight per wave; accumulation is pure per-lane VGPR FMA.
// NOTE (rounds 4-5 lesson): do NOT append tail code to this kernel — the
// allocator responds by de-batching the gather (VGPR 36 -> 20-24) and the
// kernel falls off the memory-level-parallelism cliff (41.6 -> 66-176 us).
__global__ __launch_bounds__(512, 8) void fused_kernel(
    const int* __restrict__ ti, const int* __restrict__ tl, const int* __restrict__ ns,
    const int* __restrict__ rpr_arg, const float* __restrict__ rpr_mat,
    const float* __restrict__ feat, const float* __restrict__ W,
    const float* __restrict__ emb, const float* __restrict__ nce,
    float* __restrict__ sums)
{
    int b = blockIdx.x, t = threadIdx.x, lane = t & 63, w = t >> 6;
    bool pair = (b < BATCH);
    // slab layout: [0,NV) sumInf | [NV,2NV) sumNf | [2NV,3NV) sumEmb
    //              [3NV,4NV) sumTw | [4NV,5NV) sumFw | [5NV] lossAcc
    float* slab = sums + (size_t)(b & (NSLAB - 1)) * SUMW;

    __shared__ int   nbr_sh[256];
    __shared__ float w_sh[256];
    __shared__ float part[8][FD];
    __shared__ float agg_i[FD], agg_l[FD];
    __shared__ float red[4][8];

    if (pair) {
        if (t < 256) {
            int idx = (t < 128) ? ti[b] : tl[b];      // wave-uniform scalar load
            nbr_sh[t] = rpr_arg[(size_t)idx * KNB + (t & 127)];
            w_sh[t]   = rpr_mat[(size_t)idx * KNB + (t & 127)];
        }
    } else if (t < 128) {
        int idx = ns[b - BATCH];
        nbr_sh[t] = rpr_arg[(size_t)idx * KNB + t];
        w_sh[t]   = rpr_mat[(size_t)idx * KNB + t];
    }
    __syncthreads();

    float accX = 0.f, accY = 0.f;
    {
        // pair: waves 0-3 cover nbr [0,128) (inf), waves 4-7 cover [128,256) (lf)
        // neg:  8 waves share the single row's 128 neighbors
        int nb   = pair ? 4 : 2;                  // batches of 8
        int base = pair ? (w * 32) : (w * 16);
        for (int bb = 0; bb < nb; ++bb) {
            int k0 = base + bb * 8;
            float2 d[8]; float ww[8];
            #pragma unroll
            for (int j = 0; j < 8; ++j) {
                ww[j] = w_sh[k0 + j];
                d[j]  = *(const float2*)&feat[(size_t)(unsigned)nbr_sh[k0 + j] * FD + 2 * lane];
            }
            #pragma unroll
            for (int j = 0; j < 8; ++j) {
                accX += ww[j] * d[j].x;
                accY += ww[j] * d[j].y;
            }
        }
    }
    ((float2*)part[w])[lane] = make_float2(accX, accY);   // cols 2*lane, 2*lane+1
    __syncthreads();

    if (pair) {
        if (t < FD)
            agg_i[t] = part[0][t] + part[1][t] + part[2][t] + part[3][t];
        else if (t < 2 * FD) {
            int u = t - FD;
            agg_l[u] = part[4][u] + part[5][u] + part[6][u] + part[7][u];
        }
    } else if (t < FD) {
        agg_i[t] = part[0][t] + part[1][t] + part[2][t] + part[3][t]
                 + part[4][t] + part[5][t] + part[6][t] + part[7][t];
    }
    __syncthreads();

    // dense [128]x[128,200] + relu; one W pass serves both rows
    float pi = 0.f, pl = 0.f;
    if (t < NV) {
        if (pair) {
            #pragma unroll 8
            for (int f = 0; f < FD; ++f) {
                float wv = W[f * NV + t];
                pi += agg_i[f] * wv;
                pl += agg_l[f] * wv;
            }
            pl = fmaxf(pl, 0.f);
        } else {
            #pragma unroll 8
            for (int f = 0; f < FD; ++f)
                pi += agg_i[f] * W[f * NV + t];
        }
        pi = fmaxf(pi, 0.f);
    }

    if (pair) {
        float e = 0.f, tw = 0.f;
        if (t < NV) {
            e  = emb[(size_t)ti[b] * NV + t];
            tw = nce[(size_t)tl[b] * NV + t];
            atomicAdd(&slab[t], pi);            // sumInf
            atomicAdd(&slab[2 * NV + t], e);    // sumEmb
            atomicAdd(&slab[3 * NV + t], tw);   // sumTw
        }
        float v0 = pi * pl;   // p1
        float v1 = e * tw;    // p3
        float v2 = e * pl;    // p5
        float v3 = tw * pi;   // p7
        #pragma unroll
        for (int o = 32; o > 0; o >>= 1) {
            v0 += __shfl_down(v0, o, 64);
            v1 += __shfl_down(v1, o, 64);
            v2 += __shfl_down(v2, o, 64);
            v3 += __shfl_down(v3, o, 64);
        }
        if (lane == 0) {
            red[0][w] = v0; red[1][w] = v1; red[2][w] = v2; red[3][w] = v3;
        }
        __syncthreads();
        if (t == 0) {
            float d1 = 0.f, d3 = 0.f, d5 = 0.f, d7 = 0.f;
            #pragma unroll
            for (int i = 0; i < 8; ++i) {
                d1 += red[0][i]; d3 += red[1][i]; d5 += red[2][i]; d7 += red[3][i];
            }
            float s = 1.5f * log_sig(d1) + 0.75f * log_sig(d3)
                    + 1.5f * log_sig(d5) + 1.5f * log_sig(d7);
            atomicAdd(&slab[5 * NV], s);
        }
    } else {
        if (t < NV) {
            atomicAdd(&slab[NV + t], pi);                                       // sumNf
            atomicAdd(&slab[4 * NV + t], nce[(size_t)ns[b - BATCH] * NV + t]);  // sumFw
        }
    }
}

// ---------------- slab reduce + dots of column sums + final loss ----------------
__global__ __launch_bounds__(256) void final_kernel(
    const float* __restrict__ sums, float* __restrict__ out)
{
    int t = threadIdx.x;
    float a = 0.f, bb = 0.f, c = 0.f, d = 0.f;
    if (t < NV) {
        float si = 0.f, sn = 0.f, se = 0.f, st = 0.f, sf = 0.f;
        #pragma unroll
        for (int s = 0; s < NSLAB; ++s) {
            const float* p = sums + s * SUMW;
            si += p[t];          sn += p[NV + t];     se += p[2 * NV + t];
            st += p[3 * NV + t]; sf += p[4 * NV + t];
        }
        a  = si * sn;   // sum(inf @ nf.T)
        bb = se * sf;   // sum(embed @ false_w.T)
        c  = se * sn;   // sum(embed @ nf.T)
        d  = st * sn;   // sum(true_w @ nf.T)
    }
    __shared__ float red[4][4];
    #pragma unroll
    for (int o = 32; o > 0; o >>= 1) {
        a  += __shfl_down(a, o, 64);
        bb += __shfl_down(bb, o, 64);
        c  += __shfl_down(c, o, 64);
        d  += __shfl_down(d, o, 64);
    }
    if ((t & 63) == 0) {
        int w = t >> 6;
        red[0][w] = a; red[1][w] = bb; red[2][w] = c; red[3][w] = d;
    }
    __syncthreads();
    if (t == 0) {
        float d2 = red[0][0] + red[0][1] + red[0][2] + red[0][3];
        float d4 = red[1][0] + red[1][1] + red[1][2] + red[1][3];
        float d6 = red[2][0] + red[2][1] + red[2][2] + red[2][3];
        float d8 = red[3][0] + red[3][1] + red[3][2] + red[3][3];
        float lacc = 0.f;
        #pragma unroll
        for (int s = 0; s < NSLAB; ++s) lacc += sums[s * SUMW + 5 * NV];
        float total = lacc + (float)BATCH * (1.5f * log_sig(-d2) + 0.75f * log_sig(-d4)
                                           + 1.5f * log_sig(-d6) + 1.5f * log_sig(-d8));
        out[0] = -total / (float)BATCH;
    }
}

extern "C" void kernel_launch(void* const* d_in, const int* in_sizes, int n_in,
                              void* d_out, int out_size, void* d_ws, size_t ws_size,
                              hipStream_t stream) {
    const int*   ti      = (const int*)d_in[0];
    const int*   tl      = (const int*)d_in[1];
    const int*   ns      = (const int*)d_in[2];
    const int*   rpr_arg = (const int*)d_in[3];
    const float* rpr_mat = (const float*)d_in[4];
    const float* feat    = (const float*)d_in[5];
    const float* emb     = (const float*)d_in[6];
    const float* nce     = (const float*)d_in[7];
    const float* W       = (const float*)d_in[8];

    float* sums = (float*)d_ws;   // NSLAB * SUMW floats = 32 KB

    hipMemsetAsync(d_ws, 0, (size_t)NSLAB * SUMW * sizeof(float), stream);
    fused_kernel<<<BATCH + NEG, 512, 0, stream>>>(
        ti, tl, ns, rpr_arg, rpr_mat, feat, W, emb, nce, sums);
    final_kernel<<<1, 256, 0, stream>>>(sums, (float*)d_out);
}